// Round 13
// baseline (92.150 us; speedup 1.0000x reference)
//
#include <hip/hip_runtime.h>
#include <hip/hip_bf16.h>

// SupConLoss forward. Round 13: exploit Gram symmetry — compute only col>row,
// credit each exp to BOTH row-sum and col-sum. ~53% of the N^2 work.
//  - blocks (bx: 64 row-blocks of 128, by: 32 col-chunks of 256); valid iff
//    by >= bx>>1; by == bx>>1 is the straddle block (per-element col>row mask).
//  - row credits: s_acc + shfl reduce -> rowpart[by][row] (as before).
//  - col credits: per-lane sum of its 8 values -> ds_add_f32 into colsum[256]
//    (LDS, runtime-t only in the ADDRESS, no runtime-indexed regs) ->
//    colpart[bx][col] once per block.
//  - diagonal exactly excluded by the mask (SELF_EXP correction removed).
//  - gram core unchanged: rt=2, TILE=64 double-buffered global_load_lds staging,
//    slim raw-v_exp_f32 epilogue, rolled t-loop, __launch_bounds__(256,2).
constexpr int B_SZ  = 4096;
constexpr int N_SZ  = 8192;          // B*V
constexpr int CHUNK = 256;           // cols per block
constexpr int TILE  = 64;            // cols per LDS stage
constexpr int NT    = CHUNK / TILE;  // 4
constexpr int NRB   = N_SZ / 128;    // 64 row-blocks
constexpr int NCB   = N_SZ / CHUNK;  // 32 col-chunks

typedef __attribute__((ext_vector_type(8))) __bf16 bf16x8;
typedef __attribute__((ext_vector_type(4))) float f32x4;

#define SQRT_CSC  2.1929404f         // sqrt(1/(0.3*ln2)); (c*a).(c*b) = dot/(T*ln2)
#define NEG_RATIO (-(0.3f / 0.07f))

__device__ __forceinline__ unsigned short f2bf(float f) {
    unsigned u = __float_as_uint(f);
    u += 0x7FFFu + ((u >> 16) & 1u);
    return (unsigned short)(u >> 16);
}

__device__ __forceinline__ void gl_lds16(const unsigned short* g, unsigned short* l) {
    __builtin_amdgcn_global_load_lds(
        (const __attribute__((address_space(1))) unsigned int*)g,
        (__attribute__((address_space(3))) unsigned int*)l, 16, 0, 0);
}

// feat [B,V,128] f32 -> A [N,128] bf16 scaled by sqrt(CSC); zero out[0].
__global__ __launch_bounds__(256) void prep_kernel(const float* __restrict__ feat,
                                                   unsigned short* __restrict__ A,
                                                   float* __restrict__ out) {
    const int tid = threadIdx.x;
    if (blockIdx.x == 0 && tid == 0) out[0] = 0.f;
    int t = blockIdx.x * 256 + tid;            // 0 .. 262143
    int n = t >> 5;
    int q = (t & 31) << 2;
    int b = n & (B_SZ - 1);
    int v = n >> 12;
    const float4 f = *reinterpret_cast<const float4*>(feat + (((size_t)b * 2 + v) << 7) + q);
    ushort4 o;
    o.x = f2bf(f.x * SQRT_CSC); o.y = f2bf(f.y * SQRT_CSC);
    o.z = f2bf(f.z * SQRT_CSC); o.w = f2bf(f.w * SQRT_CSC);
    *reinterpret_cast<ushort4*>(A + (((size_t)n) << 7) + q) = o;
}

// 256 blocks x 16 batch items: per-class per-d partial sums -> mpart[(c*128+d)*256+blk].
__global__ __launch_bounds__(256) void msum_kernel(const float* __restrict__ feat,
                                                   const int* __restrict__ labels,
                                                   float* __restrict__ mpart) {
    __shared__ float sm[2][256];
    const int tid = threadIdx.x;
    const int v = tid >> 7, d = tid & 127;
    const int b0 = blockIdx.x * 16;
    float a0 = 0.f, a1 = 0.f;
#pragma unroll
    for (int it = 0; it < 16; ++it) {
        const int b = b0 + it;
        const float x = feat[(((size_t)b * 2 + v) << 7) + d];
        if (labels[b]) a1 += x; else a0 += x;
    }
    sm[0][tid] = a0; sm[1][tid] = a1;
    __syncthreads();
    if (tid < 128)
        mpart[(size_t)tid * 256 + blockIdx.x] = sm[0][tid] + sm[0][tid + 128];
    else
        mpart[(size_t)tid * 256 + blockIdx.x] = sm[1][tid - 128] + sm[1][tid];
}

// 1 block: mvec[f] = sum_k mpart[f][k]; cnt = #labels==1.
__global__ __launch_bounds__(256) void mreduce_kernel(const float* __restrict__ mpart,
                                                      const int* __restrict__ labels,
                                                      float* __restrict__ mvec,
                                                      int* __restrict__ cnt) {
    __shared__ int redi[4];
    const int tid = threadIdx.x;
    const float* p = mpart + (size_t)tid * 256;
    float s = 0.f;
#pragma unroll 8
    for (int k = 0; k < 256; k += 4) {
        const float4 x = *reinterpret_cast<const float4*>(p + k);
        s += x.x + x.y + x.z + x.w;
    }
    mvec[tid] = s;
    int c = 0;
    for (int i = tid; i < B_SZ; i += 256) c += labels[i];
#pragma unroll
    for (int m = 1; m < 64; m <<= 1) c += __shfl_xor(c, m);
    if ((tid & 63) == 0) redi[tid >> 6] = c;
    __syncthreads();
    if (tid == 0) *cnt = redi[0] + redi[1] + redi[2] + redi[3];
}

// Block (bx, by): rows [128bx,128bx+128), cols [256by,256by+256). Valid iff by>=bx>>1.
// by==bx>>1: straddle (mask col>row). Credits: row-side s_acc; col-side colsum LDS.
__global__ __launch_bounds__(256, 2) void gram_kernel(const unsigned short* __restrict__ A,
                                                      float* __restrict__ rowpart,
                                                      float* __restrict__ colpart) {
    const int bx = blockIdx.x, by = blockIdx.y;
    if (by < (bx >> 1)) return;                // below-diagonal block: skip
    const bool strad = (by == (bx >> 1));

    __shared__ __align__(16) unsigned short tb[2][TILE * 128];  // 2 x 16 KB
    __shared__ float colsum[CHUNK];                              // 1 KB

    const int tid  = threadIdx.x;
    const int wave = tid >> 6;
    const int lane = tid & 63;
    const int grp  = lane >> 4;
    const int lc   = lane & 15;
    const int row0 = bx * 128 + wave * 32;
    const int col0 = by * CHUNK;

    colsum[tid] = 0.f;

    // A fragments: 2 row-tiles x 4 k-groups (frag g covers k = 32g + 8*grp + [0..8))
    bf16x8 a[2][4];
#pragma unroll
    for (int rt = 0; rt < 2; ++rt) {
        const unsigned short* ap = A + ((size_t)(row0 + 16 * rt + lc) << 7) + grp * 8;
#pragma unroll
        for (int g = 0; g < 4; ++g)
            a[rt][g] = *reinterpret_cast<const bf16x8*>(ap + g * 32);
    }

    // ct-invariant swizzled read offsets (elements): (16ct+lc)&7 == lc&7
    int off[4];
#pragma unroll
    for (int g = 0; g < 4; ++g)
        off[g] = lc * 128 + (((4 * g + grp) ^ (lc & 7)) << 3);

    float s_acc[2][4] = {{0,0,0,0},{0,0,0,0}};

    // stage tile tt: LDS slot (r,c) holds global 16B-chunk (c ^ (r&7)) of tile-row r
    auto stage = [&](int buf, int tt) {
        const unsigned short* gbase = A + ((size_t)(col0 + tt * TILE) << 7);
#pragma unroll
        for (int k = 0; k < 4; ++k) {
            const int s = tid + 256 * k;           // 0..1023 16B slots
            const int r = s >> 4, c = s & 15;
            const int src = (r << 4) + (c ^ (r & 7));
            gl_lds16(gbase + src * 8, &tb[buf][s * 8]);
        }
    };

    stage(0, 0);
    __syncthreads();

#pragma clang loop unroll(disable)
    for (int t = 0; t < NT; ++t) {
        const int cur = t & 1;
        if (t + 1 < NT) stage(cur ^ 1, t + 1);

        const unsigned short* bp = &tb[cur][0];
#pragma unroll
        for (int ct = 0; ct < 4; ++ct) {
            bf16x8 bfr[4];
#pragma unroll
            for (int g = 0; g < 4; ++g)
                bfr[g] = *reinterpret_cast<const bf16x8*>(bp + ct * 2048 + off[g]);

            f32x4 acc0 = {0,0,0,0}, acc1 = {0,0,0,0};
#pragma unroll
            for (int g = 0; g < 4; ++g) {
                acc0 = __builtin_amdgcn_mfma_f32_16x16x32_bf16(a[0][g], bfr[g], acc0, 0, 0, 0);
                acc1 = __builtin_amdgcn_mfma_f32_16x16x32_bf16(a[1][g], bfr[g], acc1, 0, 0, 0);
            }

            const int tcol = t * TILE + ct * 16 + lc;      // tile-local col 0..255
            float es0, es1;
            if (strad) {                                   // wave-uniform branch
                const int col = col0 + tcol;
                float e00 = __builtin_amdgcn_exp2f(acc0[0]);
                float e01 = __builtin_amdgcn_exp2f(acc0[1]);
                float e02 = __builtin_amdgcn_exp2f(acc0[2]);
                float e03 = __builtin_amdgcn_exp2f(acc0[3]);
                float e10 = __builtin_amdgcn_exp2f(acc1[0]);
                float e11 = __builtin_amdgcn_exp2f(acc1[1]);
                float e12 = __builtin_amdgcn_exp2f(acc1[2]);
                float e13 = __builtin_amdgcn_exp2f(acc1[3]);
                const int r0 = row0 + 4 * grp;
                e00 = (col > r0 + 0)      ? e00 : 0.f;
                e01 = (col > r0 + 1)      ? e01 : 0.f;
                e02 = (col > r0 + 2)      ? e02 : 0.f;
                e03 = (col > r0 + 3)      ? e03 : 0.f;
                e10 = (col > r0 + 16)     ? e10 : 0.f;
                e11 = (col > r0 + 17)     ? e11 : 0.f;
                e12 = (col > r0 + 18)     ? e12 : 0.f;
                e13 = (col > r0 + 19)     ? e13 : 0.f;
                s_acc[0][0] += e00; s_acc[0][1] += e01; s_acc[0][2] += e02; s_acc[0][3] += e03;
                s_acc[1][0] += e10; s_acc[1][1] += e11; s_acc[1][2] += e12; s_acc[1][3] += e13;
                es0 = (e00 + e01) + (e02 + e03);
                es1 = (e10 + e11) + (e12 + e13);
            } else {
                float e00 = __builtin_amdgcn_exp2f(acc0[0]);
                float e01 = __builtin_amdgcn_exp2f(acc0[1]);
                float e02 = __builtin_amdgcn_exp2f(acc0[2]);
                float e03 = __builtin_amdgcn_exp2f(acc0[3]);
                float e10 = __builtin_amdgcn_exp2f(acc1[0]);
                float e11 = __builtin_amdgcn_exp2f(acc1[1]);
                float e12 = __builtin_amdgcn_exp2f(acc1[2]);
                float e13 = __builtin_amdgcn_exp2f(acc1[3]);
                s_acc[0][0] += e00; s_acc[0][1] += e01; s_acc[0][2] += e02; s_acc[0][3] += e03;
                s_acc[1][0] += e10; s_acc[1][1] += e11; s_acc[1][2] += e12; s_acc[1][3] += e13;
                es0 = (e00 + e01) + (e02 + e03);
                es1 = (e10 + e11) + (e12 + e13);
            }
            atomicAdd(&colsum[tcol], es0 + es1);           // ds_add_f32, runtime addr OK
        }
        __syncthreads();
    }

    // row-side: reduce across the 16 column-lanes of each k-group
#pragma unroll
    for (int m = 1; m < 16; m <<= 1)
#pragma unroll
        for (int rt = 0; rt < 2; ++rt)
#pragma unroll
            for (int r = 0; r < 4; ++r)
                s_acc[rt][r] += __shfl_xor(s_acc[rt][r], m);

    if (lc == 0) {
        const size_t base = (size_t)by * N_SZ;
#pragma unroll
        for (int rt = 0; rt < 2; ++rt)
#pragma unroll
            for (int r = 0; r < 4; ++r)
                rowpart[base + row0 + 16 * rt + 4 * grp + r] = s_acc[rt][r];
    }

    __syncthreads();   // colsum complete (last loop barrier covers ds_adds; this orders the write below)
    colpart[(size_t)bx * N_SZ + col0 + tid] = colsum[tid];
}

// Grid 32 x 256: S[i] = sum_{by>=i/256} rowpart[by][i] + sum_{bx<=2(i/256)+1} colpart[bx][i];
// P via f32 dot with class mean; loss; atomic out.
__global__ __launch_bounds__(256) void final_kernel(const float* __restrict__ rowpart,
                                                    const float* __restrict__ colpart,
                                                    const float* __restrict__ feat,
                                                    const int* __restrict__ labels,
                                                    const float* __restrict__ mvec,
                                                    const int* __restrict__ cnt,
                                                    float* __restrict__ out) {
    __shared__ float red[4];
    const int tid = threadIdx.x;
    const int i = blockIdx.x * 256 + tid;
    const int cb = i >> 8;                      // 256-chunk index of i

    float S = 0.f;
    for (int by = cb; by < NCB; ++by) S += rowpart[(size_t)by * N_SZ + i];
    const int bxMax = 2 * cb + 1;
    for (int bxx = 0; bxx <= bxMax; ++bxx) S += colpart[(size_t)bxx * N_SZ + i];

    const int b = i & (B_SZ - 1), v = i >> 12;
    const int lab = labels[b];
    const float* fr = feat + (((size_t)b * 2 + v) << 7);
    const float* mv = mvec + (lab ? 128 : 0);
    float dot = 0.f;
#pragma unroll 8
    for (int d = 0; d < 128; d += 4) {
        const float4 x = *reinterpret_cast<const float4*>(fr + d);
        const float4 y = *reinterpret_cast<const float4*>(mv + d);
        dot += x.x * y.x + x.y * y.y + x.z * y.z + x.w * y.w;
    }

    const int c1 = *cnt;
    const int cs = lab ? c1 : (B_SZ - c1);
    const float n = (float)(2 * cs - 1);
    float term = ((dot - 1.0f) * (1.0f / 0.3f) - n * logf(S + 1e-8f)) / (n + 1e-8f);

#pragma unroll
    for (int m = 1; m < 64; m <<= 1) term += __shfl_xor(term, m);
    if ((tid & 63) == 0) red[tid >> 6] = term;
    __syncthreads();
    if (tid == 0)
        atomicAdd(out, (red[0] + red[1] + red[2] + red[3]) * (NEG_RATIO / (float)N_SZ));
}

extern "C" void kernel_launch(void* const* d_in, const int* in_sizes, int n_in,
                              void* d_out, int out_size, void* d_ws, size_t ws_size,
                              hipStream_t stream) {
    const float* feat = (const float*)d_in[0];
    const int* labels = (const int*)d_in[1];
    float* out = (float*)d_out;

    char* ws = (char*)d_ws;
    unsigned short* A = (unsigned short*)ws;                              // 2 MB
    float* rowpart = (float*)(ws + (size_t)2 * 1024 * 1024);              // 1 MB   (32 x 8192)
    float* colpart = (float*)(ws + (size_t)3 * 1024 * 1024);              // 2 MB   (64 x 8192)
    float* mpart   = (float*)(ws + (size_t)5 * 1024 * 1024);              // 256 KB
    float* mvec    = (float*)(ws + (size_t)5 * 1024 * 1024 + 256 * 1024); // 1 KB
    int*   cnt     = (int*)(ws + (size_t)5 * 1024 * 1024 + 257 * 1024);   // 4 B

    prep_kernel<<<dim3(1024), dim3(256), 0, stream>>>(feat, A, out);
    msum_kernel<<<dim3(256), dim3(256), 0, stream>>>(feat, labels, mpart);
    mreduce_kernel<<<dim3(1), dim3(256), 0, stream>>>(mpart, labels, mvec, cnt);
    gram_kernel<<<dim3(NRB, NCB), dim3(256), 0, stream>>>(A, rowpart, colpart);
    final_kernel<<<dim3(N_SZ / 256), dim3(256), 0, stream>>>(rowpart, colpart, feat, labels, mvec, cnt, out);
}

// Round 14
// 73.626 us; speedup vs baseline: 1.2516x; 1.2516x over previous
//
#include <hip/hip_runtime.h>
#include <hip/hip_bf16.h>

// SupConLoss forward. Round 14: round-11 gram (proven best, untouched) + launch
// fusion: 5 kernels -> 3.
//  - prep absorbs msum (convert + per-block class sums via LDS atomics -> mpart).
//  - final absorbs mreduce (each final block redundantly reduces mpart + counts
//    labels; 32 x 1MB L2 reads ~ 1us aggregate).
//  - gram: rt=2, CHUNK=512, TILE=64 dbuf global_load_lds, slim v_exp_f32 epilogue,
//    diagonal subtracted analytically, rolled t-loop, __launch_bounds__(256,2).
//  - P_i = f_i . m_{lab_i} - 1 exact in f32; gram computes S only (exp2+add).
constexpr int B_SZ  = 4096;
constexpr int N_SZ  = 8192;          // B*V
constexpr int CHUNK = 512;           // cols per block
constexpr int TILE  = 64;            // cols per LDS stage
constexpr int NT    = CHUNK / TILE;  // 8
constexpr int NCH   = N_SZ / CHUNK;  // 16
constexpr int BROWS = 128;           // rows per block (4 waves x 32)
constexpr int MP_W  = 1024;          // mpart width = prep grid size

typedef __attribute__((ext_vector_type(8))) __bf16 bf16x8;
typedef __attribute__((ext_vector_type(4))) float f32x4;

#define SQRT_CSC  2.1929404f         // sqrt(1/(0.3*ln2)); (c*a).(c*b) = dot/(T*ln2)
#define SELF_EXP  28.0316248f        // exp2(CSC) = e^{1/0.3}: analytic diagonal term
#define NEG_RATIO (-(0.3f / 0.07f))

__device__ __forceinline__ unsigned short f2bf(float f) {
    unsigned u = __float_as_uint(f);
    u += 0x7FFFu + ((u >> 16) & 1u);
    return (unsigned short)(u >> 16);
}

__device__ __forceinline__ void gl_lds16(const unsigned short* g, unsigned short* l) {
    __builtin_amdgcn_global_load_lds(
        (const __attribute__((address_space(1))) unsigned int*)g,
        (__attribute__((address_space(3))) unsigned int*)l, 16, 0, 0);
}

// feat [B,V,128] f32 -> A [N,128] bf16 scaled by sqrt(CSC);
// fused class-mean partials: mpart[(c*128+d)*MP_W + blk]; zero out[0].
__global__ __launch_bounds__(256) void prep_kernel(const float* __restrict__ feat,
                                                   const int* __restrict__ labels,
                                                   unsigned short* __restrict__ A,
                                                   float* __restrict__ mpart,
                                                   float* __restrict__ out) {
    __shared__ float cls[256];                 // [2][128] class sums for this block
    const int tid = threadIdx.x;
    cls[tid] = 0.f;
    __syncthreads();

    const int t = blockIdx.x * 256 + tid;      // 0 .. 262143
    const int n = t >> 5;                      // output row (view-major)
    const int q = (t & 31) << 2;               // d offset
    const int b = n & (B_SZ - 1);
    const int v = n >> 12;
    const float4 f = *reinterpret_cast<const float4*>(feat + (((size_t)b * 2 + v) << 7) + q);
    ushort4 o;
    o.x = f2bf(f.x * SQRT_CSC); o.y = f2bf(f.y * SQRT_CSC);
    o.z = f2bf(f.z * SQRT_CSC); o.w = f2bf(f.w * SQRT_CSC);
    *reinterpret_cast<ushort4*>(A + (((size_t)n) << 7) + q) = o;

    float* c = &cls[(labels[b] ? 128 : 0) + q];
    atomicAdd(c + 0, f.x); atomicAdd(c + 1, f.y);
    atomicAdd(c + 2, f.z); atomicAdd(c + 3, f.w);
    __syncthreads();
    mpart[(size_t)tid * MP_W + blockIdx.x] = cls[tid];
    if (blockIdx.x == 0 && tid == 0) out[0] = 0.f;
}

// Block: 4 waves x 32 rows = 128 rows, one 512-col chunk, LDS-staged 64-col tiles.
__global__ __launch_bounds__(256, 2) void gram_kernel(const unsigned short* __restrict__ A,
                                                      float* __restrict__ S_part) {
    __shared__ __align__(16) unsigned short tb[2][TILE * 128];  // 2 x 16 KB

    const int tid  = threadIdx.x;
    const int wave = tid >> 6;
    const int lane = tid & 63;
    const int grp  = lane >> 4;
    const int lc   = lane & 15;
    const int row0 = blockIdx.x * BROWS + wave * 32;
    const int col0 = blockIdx.y * CHUNK;

    // A fragments: 2 row-tiles x 4 k-groups (frag g covers k = 32g + 8*grp + [0..8))
    bf16x8 a[2][4];
#pragma unroll
    for (int rt = 0; rt < 2; ++rt) {
        const unsigned short* ap = A + ((size_t)(row0 + 16 * rt + lc) << 7) + grp * 8;
#pragma unroll
        for (int g = 0; g < 4; ++g)
            a[rt][g] = *reinterpret_cast<const bf16x8*>(ap + g * 32);
    }

    // ct-invariant swizzled read offsets (elements): (16ct+lc)&7 == lc&7
    int off[4];
#pragma unroll
    for (int g = 0; g < 4; ++g)
        off[g] = lc * 128 + (((4 * g + grp) ^ (lc & 7)) << 3);

    float s_acc[2][4] = {{0,0,0,0},{0,0,0,0}};

    // stage tile tt: LDS slot (r,c) holds global 16B-chunk (c ^ (r&7)) of tile-row r
    auto stage = [&](int buf, int tt) {
        const unsigned short* gbase = A + ((size_t)(col0 + tt * TILE) << 7);
#pragma unroll
        for (int k = 0; k < 4; ++k) {
            const int s = tid + 256 * k;           // 0..1023 16B slots
            const int r = s >> 4, c = s & 15;
            const int src = (r << 4) + (c ^ (r & 7));
            gl_lds16(gbase + src * 8, &tb[buf][s * 8]);
        }
    };

    stage(0, 0);
    __syncthreads();

#pragma clang loop unroll(disable)
    for (int t = 0; t < NT; ++t) {
        const int cur = t & 1;
        if (t + 1 < NT) stage(cur ^ 1, t + 1);

        const unsigned short* bp = &tb[cur][0];
#pragma unroll
        for (int ct = 0; ct < 4; ++ct) {
            bf16x8 bfr[4];
#pragma unroll
            for (int g = 0; g < 4; ++g)
                bfr[g] = *reinterpret_cast<const bf16x8*>(bp + ct * 2048 + off[g]);

            f32x4 acc0 = {0,0,0,0}, acc1 = {0,0,0,0};
#pragma unroll
            for (int g = 0; g < 4; ++g) {
                acc0 = __builtin_amdgcn_mfma_f32_16x16x32_bf16(a[0][g], bfr[g], acc0, 0, 0, 0);
                acc1 = __builtin_amdgcn_mfma_f32_16x16x32_bf16(a[1][g], bfr[g], acc1, 0, 0, 0);
            }
            // uniform epilogue: raw v_exp_f32; diagonal subtracted analytically in final
#pragma unroll
            for (int r = 0; r < 4; ++r) {
                s_acc[0][r] += __builtin_amdgcn_exp2f(acc0[r]);
                s_acc[1][r] += __builtin_amdgcn_exp2f(acc1[r]);
            }
        }
        __syncthreads();
    }

    // reduce across the 16 column-lanes of each k-group
#pragma unroll
    for (int m = 1; m < 16; m <<= 1)
#pragma unroll
        for (int rt = 0; rt < 2; ++rt)
#pragma unroll
            for (int r = 0; r < 4; ++r)
                s_acc[rt][r] += __shfl_xor(s_acc[rt][r], m);

    if (lc == 0) {
        const size_t base = (size_t)blockIdx.y * N_SZ;
#pragma unroll
        for (int rt = 0; rt < 2; ++rt)
#pragma unroll
            for (int r = 0; r < 4; ++r)
                S_part[base + row0 + 16 * rt + 4 * grp + r] = s_acc[rt][r];
    }
}

// Grid 32 x 256: reduce mpart -> mv (LDS) + count labels (fused mreduce), combine
// 16 S-partials/row minus analytic self-term, P via f32 dot with class mean,
// loss terms, atomic out.
__global__ __launch_bounds__(256) void final_kernel(const float* __restrict__ S_part,
                                                    const float* __restrict__ feat,
                                                    const int* __restrict__ labels,
                                                    const float* __restrict__ mpart,
                                                    float* __restrict__ out) {
    __shared__ float mv[256];
    __shared__ float red[4];
    __shared__ int   redi[4];
    const int tid = threadIdx.x;

    // mv[tid] = sum over MP_W prep-block partials of (class,d) slot tid
    {
        const float* p = mpart + (size_t)tid * MP_W;
        float s = 0.f;
#pragma unroll 4
        for (int k = 0; k < MP_W; k += 4) {
            const float4 x = *reinterpret_cast<const float4*>(p + k);
            s += x.x + x.y + x.z + x.w;
        }
        mv[tid] = s;
    }

    // label count
    int c = 0;
    for (int i = tid; i < B_SZ; i += 256) c += labels[i];
#pragma unroll
    for (int m = 1; m < 64; m <<= 1) c += __shfl_xor(c, m);
    if ((tid & 63) == 0) redi[tid >> 6] = c;
    __syncthreads();
    const int c1 = redi[0] + redi[1] + redi[2] + redi[3];

    const int i = blockIdx.x * 256 + tid;
    float S = -SELF_EXP;
#pragma unroll
    for (int k = 0; k < NCH; ++k) S += S_part[(size_t)k * N_SZ + i];

    const int b = i & (B_SZ - 1), v = i >> 12;
    const int lab = labels[b];
    const float* fr = feat + (((size_t)b * 2 + v) << 7);
    const float* mvp = &mv[lab ? 128 : 0];
    float dot = 0.f;
#pragma unroll 8
    for (int d = 0; d < 128; d += 4) {
        const float4 x = *reinterpret_cast<const float4*>(fr + d);
        dot += x.x * mvp[d] + x.y * mvp[d + 1] + x.z * mvp[d + 2] + x.w * mvp[d + 3];
    }

    const int cs = lab ? c1 : (B_SZ - c1);
    const float n = (float)(2 * cs - 1);
    float term = ((dot - 1.0f) * (1.0f / 0.3f) - n * logf(S + 1e-8f)) / (n + 1e-8f);

#pragma unroll
    for (int m = 1; m < 64; m <<= 1) term += __shfl_xor(term, m);
    if ((tid & 63) == 0) red[tid >> 6] = term;
    __syncthreads();
    if (tid == 0)
        atomicAdd(out, (red[0] + red[1] + red[2] + red[3]) * (NEG_RATIO / (float)N_SZ));
}

extern "C" void kernel_launch(void* const* d_in, const int* in_sizes, int n_in,
                              void* d_out, int out_size, void* d_ws, size_t ws_size,
                              hipStream_t stream) {
    const float* feat = (const float*)d_in[0];
    const int* labels = (const int*)d_in[1];
    float* out = (float*)d_out;

    char* ws = (char*)d_ws;
    unsigned short* A = (unsigned short*)ws;                              // 2 MB
    float* S_part = (float*)(ws + (size_t)2 * 1024 * 1024);               // 512 KB
    float* mpart  = (float*)(ws + (size_t)2 * 1024 * 1024 + 512 * 1024);  // 1 MB

    prep_kernel<<<dim3(1024), dim3(256), 0, stream>>>(feat, labels, A, mpart, out);
    gram_kernel<<<dim3(N_SZ / BROWS, NCH), dim3(256), 0, stream>>>(A, S_part);
    final_kernel<<<dim3(N_SZ / 256), dim3(256), 0, stream>>>(S_part, feat, labels, mpart, out);
}

// Round 15
// 47.417 us; speedup vs baseline: 1.9434x; 1.5528x over previous
//
#include <hip/hip_runtime.h>
#include <hip/hip_bf16.h>

// SupConLoss forward. Round 15: round-11 (best, 50.0us) with the one layout-safe
// fusion: mreduce folded into final (each final block redundantly reduces the
// 256KB mpart via L1-friendly row reads + counts labels). prep/msum/gram are
// byte-identical to round 11. 4 launches.
//  - gram: rt=2, CHUNK=512, TILE=64 dbuf global_load_lds, slim v_exp_f32 epilogue,
//    diagonal subtracted analytically in final, rolled t-loop, (256,2).
//  - P_i = f_i . m_{lab_i} - 1 exact in f32; gram computes S only (exp2+add).
constexpr int B_SZ  = 4096;
constexpr int N_SZ  = 8192;          // B*V
constexpr int CHUNK = 512;           // cols per block
constexpr int TILE  = 64;            // cols per LDS stage
constexpr int NT    = CHUNK / TILE;  // 8
constexpr int NCH   = N_SZ / CHUNK;  // 16
constexpr int BROWS = 128;           // rows per block (4 waves x 32)

typedef __attribute__((ext_vector_type(8))) __bf16 bf16x8;
typedef __attribute__((ext_vector_type(4))) float f32x4;

#define SQRT_CSC  2.1929404f         // sqrt(1/(0.3*ln2)); (c*a).(c*b) = dot/(T*ln2)
#define SELF_EXP  28.0316248f        // exp2(CSC) = e^{1/0.3}: analytic diagonal term
#define NEG_RATIO (-(0.3f / 0.07f))

__device__ __forceinline__ unsigned short f2bf(float f) {
    unsigned u = __float_as_uint(f);
    u += 0x7FFFu + ((u >> 16) & 1u);
    return (unsigned short)(u >> 16);
}

__device__ __forceinline__ void gl_lds16(const unsigned short* g, unsigned short* l) {
    __builtin_amdgcn_global_load_lds(
        (const __attribute__((address_space(1))) unsigned int*)g,
        (__attribute__((address_space(3))) unsigned int*)l, 16, 0, 0);
}

// feat [B,V,128] f32 -> A [N,128] bf16 scaled by sqrt(CSC); zero out[0].
__global__ __launch_bounds__(256) void prep_kernel(const float* __restrict__ feat,
                                                   unsigned short* __restrict__ A,
                                                   float* __restrict__ out) {
    const int tid = threadIdx.x;
    if (blockIdx.x == 0 && tid == 0) out[0] = 0.f;
    int t = blockIdx.x * 256 + tid;            // 0 .. 262143
    int n = t >> 5;
    int q = (t & 31) << 2;
    int b = n & (B_SZ - 1);
    int v = n >> 12;
    const float4 f = *reinterpret_cast<const float4*>(feat + (((size_t)b * 2 + v) << 7) + q);
    ushort4 o;
    o.x = f2bf(f.x * SQRT_CSC); o.y = f2bf(f.y * SQRT_CSC);
    o.z = f2bf(f.z * SQRT_CSC); o.w = f2bf(f.w * SQRT_CSC);
    *reinterpret_cast<ushort4*>(A + (((size_t)n) << 7) + q) = o;
}

// 256 blocks x 16 batch items: per-class per-d partial sums -> mpart[(c*128+d)*256+blk].
__global__ __launch_bounds__(256) void msum_kernel(const float* __restrict__ feat,
                                                   const int* __restrict__ labels,
                                                   float* __restrict__ mpart) {
    __shared__ float sm[2][256];
    const int tid = threadIdx.x;
    const int v = tid >> 7, d = tid & 127;
    const int b0 = blockIdx.x * 16;
    float a0 = 0.f, a1 = 0.f;
#pragma unroll
    for (int it = 0; it < 16; ++it) {
        const int b = b0 + it;
        const float x = feat[(((size_t)b * 2 + v) << 7) + d];
        if (labels[b]) a1 += x; else a0 += x;
    }
    sm[0][tid] = a0; sm[1][tid] = a1;
    __syncthreads();
    if (tid < 128)
        mpart[(size_t)tid * 256 + blockIdx.x] = sm[0][tid] + sm[0][tid + 128];
    else
        mpart[(size_t)tid * 256 + blockIdx.x] = sm[1][tid - 128] + sm[1][tid];
}

// Block: 4 waves x 32 rows = 128 rows, one 512-col chunk, LDS-staged 64-col tiles.
__global__ __launch_bounds__(256, 2) void gram_kernel(const unsigned short* __restrict__ A,
                                                      float* __restrict__ S_part) {
    __shared__ __align__(16) unsigned short tb[2][TILE * 128];  // 2 x 16 KB

    const int tid  = threadIdx.x;
    const int wave = tid >> 6;
    const int lane = tid & 63;
    const int grp  = lane >> 4;
    const int lc   = lane & 15;
    const int row0 = blockIdx.x * BROWS + wave * 32;
    const int col0 = blockIdx.y * CHUNK;

    // A fragments: 2 row-tiles x 4 k-groups (frag g covers k = 32g + 8*grp + [0..8))
    bf16x8 a[2][4];
#pragma unroll
    for (int rt = 0; rt < 2; ++rt) {
        const unsigned short* ap = A + ((size_t)(row0 + 16 * rt + lc) << 7) + grp * 8;
#pragma unroll
        for (int g = 0; g < 4; ++g)
            a[rt][g] = *reinterpret_cast<const bf16x8*>(ap + g * 32);
    }

    // ct-invariant swizzled read offsets (elements): (16ct+lc)&7 == lc&7
    int off[4];
#pragma unroll
    for (int g = 0; g < 4; ++g)
        off[g] = lc * 128 + (((4 * g + grp) ^ (lc & 7)) << 3);

    float s_acc[2][4] = {{0,0,0,0},{0,0,0,0}};

    // stage tile tt: LDS slot (r,c) holds global 16B-chunk (c ^ (r&7)) of tile-row r
    auto stage = [&](int buf, int tt) {
        const unsigned short* gbase = A + ((size_t)(col0 + tt * TILE) << 7);
#pragma unroll
        for (int k = 0; k < 4; ++k) {
            const int s = tid + 256 * k;           // 0..1023 16B slots
            const int r = s >> 4, c = s & 15;
            const int src = (r << 4) + (c ^ (r & 7));
            gl_lds16(gbase + src * 8, &tb[buf][s * 8]);
        }
    };

    stage(0, 0);
    __syncthreads();

#pragma clang loop unroll(disable)
    for (int t = 0; t < NT; ++t) {
        const int cur = t & 1;
        if (t + 1 < NT) stage(cur ^ 1, t + 1);

        const unsigned short* bp = &tb[cur][0];
#pragma unroll
        for (int ct = 0; ct < 4; ++ct) {
            bf16x8 bfr[4];
#pragma unroll
            for (int g = 0; g < 4; ++g)
                bfr[g] = *reinterpret_cast<const bf16x8*>(bp + ct * 2048 + off[g]);

            f32x4 acc0 = {0,0,0,0}, acc1 = {0,0,0,0};
#pragma unroll
            for (int g = 0; g < 4; ++g) {
                acc0 = __builtin_amdgcn_mfma_f32_16x16x32_bf16(a[0][g], bfr[g], acc0, 0, 0, 0);
                acc1 = __builtin_amdgcn_mfma_f32_16x16x32_bf16(a[1][g], bfr[g], acc1, 0, 0, 0);
            }
            // uniform epilogue: raw v_exp_f32; diagonal subtracted analytically in final
#pragma unroll
            for (int r = 0; r < 4; ++r) {
                s_acc[0][r] += __builtin_amdgcn_exp2f(acc0[r]);
                s_acc[1][r] += __builtin_amdgcn_exp2f(acc1[r]);
            }
        }
        __syncthreads();
    }

    // reduce across the 16 column-lanes of each k-group
#pragma unroll
    for (int m = 1; m < 16; m <<= 1)
#pragma unroll
        for (int rt = 0; rt < 2; ++rt)
#pragma unroll
            for (int r = 0; r < 4; ++r)
                s_acc[rt][r] += __shfl_xor(s_acc[rt][r], m);

    if (lc == 0) {
        const size_t base = (size_t)blockIdx.y * N_SZ;
#pragma unroll
        for (int rt = 0; rt < 2; ++rt)
#pragma unroll
            for (int r = 0; r < 4; ++r)
                S_part[base + row0 + 16 * rt + 4 * grp + r] = s_acc[rt][r];
    }
}

// Grid 32 x 256: fused mreduce (per-block: mv[tid] = sum of mpart row tid — rows are
// contiguous, L1-consumed whole lines; label count), then combine 16 S-partials/row
// minus analytic self-term, P via f32 dot with class mean, loss terms, atomic out.
__global__ __launch_bounds__(256) void final_kernel(const float* __restrict__ S_part,
                                                    const float* __restrict__ feat,
                                                    const int* __restrict__ labels,
                                                    const float* __restrict__ mpart,
                                                    float* __restrict__ out) {
    __shared__ float mv[256];
    __shared__ float red[4];
    __shared__ int   redi[4];
    const int tid = threadIdx.x;

    // mv[tid] = sum over the 256 msum-block partials of (class,d) slot tid
    {
        const float* p = mpart + (size_t)tid * 256;
        float s = 0.f;
#pragma unroll 8
        for (int k = 0; k < 256; k += 4) {
            const float4 x = *reinterpret_cast<const float4*>(p + k);
            s += x.x + x.y + x.z + x.w;
        }
        mv[tid] = s;
    }

    // label count
    int c = 0;
    for (int i = tid; i < B_SZ; i += 256) c += labels[i];
#pragma unroll
    for (int m = 1; m < 64; m <<= 1) c += __shfl_xor(c, m);
    if ((tid & 63) == 0) redi[tid >> 6] = c;
    __syncthreads();                 // also publishes mv[]
    const int c1 = redi[0] + redi[1] + redi[2] + redi[3];

    const int i = blockIdx.x * 256 + tid;
    float S = -SELF_EXP;
#pragma unroll
    for (int k = 0; k < NCH; ++k) S += S_part[(size_t)k * N_SZ + i];

    const int b = i & (B_SZ - 1), v = i >> 12;
    const int lab = labels[b];
    const float* fr = feat + (((size_t)b * 2 + v) << 7);
    const float* mvp = &mv[lab ? 128 : 0];
    float dot = 0.f;
#pragma unroll 8
    for (int d = 0; d < 128; d += 4) {
        const float4 x = *reinterpret_cast<const float4*>(fr + d);
        dot += x.x * mvp[d] + x.y * mvp[d + 1] + x.z * mvp[d + 2] + x.w * mvp[d + 3];
    }

    const int cs = lab ? c1 : (B_SZ - c1);
    const float n = (float)(2 * cs - 1);
    float term = ((dot - 1.0f) * (1.0f / 0.3f) - n * logf(S + 1e-8f)) / (n + 1e-8f);

#pragma unroll
    for (int m = 1; m < 64; m <<= 1) term += __shfl_xor(term, m);
    if ((tid & 63) == 0) red[tid >> 6] = term;
    __syncthreads();
    if (tid == 0)
        atomicAdd(out, (red[0] + red[1] + red[2] + red[3]) * (NEG_RATIO / (float)N_SZ));
}

extern "C" void kernel_launch(void* const* d_in, const int* in_sizes, int n_in,
                              void* d_out, int out_size, void* d_ws, size_t ws_size,
                              hipStream_t stream) {
    const float* feat = (const float*)d_in[0];
    const int* labels = (const int*)d_in[1];
    float* out = (float*)d_out;

    char* ws = (char*)d_ws;
    unsigned short* A = (unsigned short*)ws;                             // 2 MB
    float* S_part = (float*)(ws + (size_t)2 * 1024 * 1024);              // 512 KB
    float* mpart  = (float*)(ws + (size_t)2 * 1024 * 1024 + 512 * 1024); // 256 KB

    prep_kernel<<<dim3(1024), dim3(256), 0, stream>>>(feat, A, out);
    msum_kernel<<<dim3(256), dim3(256), 0, stream>>>(feat, labels, mpart);
    gram_kernel<<<dim3(N_SZ / BROWS, NCH), dim3(256), 0, stream>>>(A, S_part);
    final_kernel<<<dim3(N_SZ / 256), dim3(256), 0, stream>>>(S_part, feat, labels, mpart, out);
}